// Round 3
// baseline (6656.707 us; speedup 1.0000x reference)
//
#include <hip/hip_runtime.h>

typedef _Float16 f16;
typedef __attribute__((ext_vector_type(8))) _Float16 f16x8;
typedef __attribute__((ext_vector_type(4))) float f32x4;

#define BD 64      // state dim D
#define HW 512     // hidden width W
#define TT 16      // time points T
#define BR 16      // batch rows per block
#define NBLK 32    // 512 / 16
#define NTHREADS 512

// lgkm-only barrier: protects LDS producer->consumer without draining vmcnt
// (keeps the W1 global-load stream in flight across phase boundaries)
#define LBAR() asm volatile("s_waitcnt lgkmcnt(0)\n\ts_barrier" ::: "memory")

// Tsit5 coefficients
constexpr float cA21 = 0.161f;
constexpr float cA31 = -0.008480655492356989f, cA32 = 0.335480655492357f;
constexpr float cA41 = 2.8971530571054935f, cA42 = -6.359448489975075f, cA43 = 4.3622954328695815f;
constexpr float cA51 = 5.325864828439257f, cA52 = -11.748883564062828f, cA53 = 7.4955393428898365f, cA54 = -0.09249506636175525f;
constexpr float cA61 = 5.86145544294642f, cA62 = -12.92096931784711f, cA63 = 8.159367898576159f, cA64 = -0.071584973281401f, cA65 = -0.028269050394068383f;
constexpr float cB1 = 0.09646076681806523f, cB2 = 0.01f, cB3 = 0.4798896504144996f;
constexpr float cB4 = 1.379008574103742f, cB5 = -3.290069515436081f, cB6 = 2.324710524099774f;

__device__ __forceinline__ float softplus_f(float x) {
  return fmaxf(x, 0.0f) + __logf(1.0f + __expf(-fabsf(x)));
}

// convert W0 [512,64], W1 [512,512], W2 [64,512] (row-major f32) to fp16 in ws
__global__ void cvt_kernel(const float* __restrict__ w0,
                           const float* __restrict__ w1,
                           const float* __restrict__ w2,
                           f16* __restrict__ wsh) {
  int i = blockIdx.x * 512 + threadIdx.x;
  if (i < 32768) wsh[i] = (f16)w0[i];
  else if (i < 294912) wsh[i] = (f16)w1[i - 32768];
  else if (i < 327680) wsh[i] = (f16)w2[i - 294912];
}

__global__ __launch_bounds__(NTHREADS)
__attribute__((amdgpu_waves_per_eu(2, 2)))   // pin 2 waves/SIMD -> 256 VGPR budget, no spill-balancing
void ode_kernel(const float* __restrict__ ts,
                const float* __restrict__ y0,
                const float* __restrict__ b0,
                const float* __restrict__ b1,
                const float* __restrict__ b2,
                const f16* __restrict__ W0h,
                const f16* __restrict__ W1h,
                const f16* __restrict__ W2h,
                float* __restrict__ out) {
  __shared__ __align__(16) f16 h0buf[BR][HW + 8];
  __shared__ __align__(16) f16 h1buf[BR][HW + 8];
  __shared__ __align__(16) f16 atile[BR][BD + 8];
  // k stored as two K-halves (split-K layer 3, no reduce barrier); summed in COMBINE
  __shared__ float kbuf[2][6][BR][BD];
  __shared__ float ybuf[BR][BD];

  const int tid = threadIdx.x;
  const int wave = tid >> 6;
  const int lane = tid & 63;
  const int m = lane & 15;   // A-row / B-col / D-col index
  const int g = lane >> 4;   // lane group 0..3
  const int row0 = blockIdx.x * BR;
  const int cbase = wave * 64;   // layer1/2 output-column base for this wave
  const int ntile = wave & 3;    // layer3 output col tile
  const int kh = wave >> 2;      // layer3 K half

  // per-thread W1 base pointer: row (cbase+m), col g*8; offsets nt*8192 + kt*32
  const f16* const W1p = W1h + (cbase + m) * HW + g * 8;

  // ---- preload loop-invariant weights/biases into registers ----
  f16x8 w0r[2][4];                       // 32 VGPR
#pragma unroll
  for (int kt = 0; kt < 2; ++kt)
#pragma unroll
    for (int nt = 0; nt < 4; ++nt)
      w0r[kt][nt] = *(const f16x8*)&W0h[(cbase + nt * 16 + m) * BD + kt * 32 + g * 8];
  f16x8 w2r[8];                          // 32 VGPR (per-wave K-half of W2 tile)
#pragma unroll
  for (int kt = 0; kt < 8; ++kt)
    w2r[kt] = *(const f16x8*)&W2h[(ntile * 16 + m) * HW + kh * 256 + kt * 32 + g * 8];
  float bias0[4], bias1[4];
#pragma unroll
  for (int nt = 0; nt < 4; ++nt) {
    bias0[nt] = b0[cbase + nt * 16 + m];
    bias1[nt] = b1[cbase + nt * 16 + m];
  }
  const float bias2 = (kh == 0) ? b2[ntile * 16 + m] : 0.0f;

  // ---- init: y0 into LDS (f32) + atile (f16), write t=0 output ----
  for (int e = tid; e < BR * BD; e += NTHREADS) {
    const int r = e >> 6, d = e & 63;
    const float v = y0[(row0 + r) * BD + d];
    ybuf[r][d] = v;
    atile[r][d] = (f16)v;
    out[(row0 + r) * (TT * BD) + d] = v;
  }
  LBAR();

  // f(atile) -> kbuf[*][kidx]  (one MLP eval for this block's 16 rows)
  auto feval = [&](int kidx) {
    // ---- issue first 8 W1 k-tiles immediately (in flight during layer 1) ----
    f16x8 bpre[8][4];                    // 128 VGPR ring
#pragma unroll
    for (int p = 0; p < 8; ++p)
#pragma unroll
      for (int nt = 0; nt < 4; ++nt)
        bpre[p][nt] = *(const f16x8*)&W1p[nt * 16 * HW + p * 32];

    // ---- layer 1: h0 = softplus(atile @ W0^T + b0); B from registers
    {
      f32x4 acc[4] = {{0.f,0.f,0.f,0.f},{0.f,0.f,0.f,0.f},{0.f,0.f,0.f,0.f},{0.f,0.f,0.f,0.f}};
#pragma unroll
      for (int kt = 0; kt < 2; ++kt) {
        const f16x8 a = *(const f16x8*)&atile[m][kt * 32 + g * 8];
#pragma unroll
        for (int nt = 0; nt < 4; ++nt)
          acc[nt] = __builtin_amdgcn_mfma_f32_16x16x32_f16(a, w0r[kt][nt], acc[nt], 0, 0, 0);
      }
#pragma unroll
      for (int nt = 0; nt < 4; ++nt) {
        const int n = cbase + nt * 16 + m;
#pragma unroll
        for (int j = 0; j < 4; ++j)
          h0buf[g * 4 + j][n] = (f16)softplus_f(acc[nt][j] + bias0[nt]);
      }
    }
    LBAR();
    // ---- layer 2: h1 = softplus(h0 @ W1^T + b1); depth-8 ring, refill during kt=0..7
    {
      f32x4 acc[4] = {{0.f,0.f,0.f,0.f},{0.f,0.f,0.f,0.f},{0.f,0.f,0.f,0.f},{0.f,0.f,0.f,0.f}};
#pragma unroll
      for (int kt = 0; kt < 16; ++kt) {
        const f16x8 a = *(const f16x8*)&h0buf[m][kt * 32 + g * 8];
#pragma unroll
        for (int nt = 0; nt < 4; ++nt)
          acc[nt] = __builtin_amdgcn_mfma_f32_16x16x32_f16(a, bpre[kt & 7][nt], acc[nt], 0, 0, 0);
        if (kt < 8) {
#pragma unroll
          for (int nt = 0; nt < 4; ++nt)
            bpre[kt & 7][nt] = *(const f16x8*)&W1p[nt * 16 * HW + (kt + 8) * 32];
        }
      }
#pragma unroll
      for (int nt = 0; nt < 4; ++nt) {
        const int n = cbase + nt * 16 + m;
#pragma unroll
        for (int j = 0; j < 4; ++j)
          h1buf[g * 4 + j][n] = (f16)softplus_f(acc[nt][j] + bias1[nt]);
      }
    }
    LBAR();
    // ---- layer 3: k = h1 @ W2^T + b2; split-K across wave halves, B from registers
    {
      f32x4 acc = {0.f, 0.f, 0.f, 0.f};
#pragma unroll
      for (int kt = 0; kt < 8; ++kt) {
        const f16x8 a = *(const f16x8*)&h1buf[m][kh * 256 + kt * 32 + g * 8];
        acc = __builtin_amdgcn_mfma_f32_16x16x32_f16(a, w2r[kt], acc, 0, 0, 0);
      }
#pragma unroll
      for (int j = 0; j < 4; ++j)
        kbuf[kh][kidx][g * 4 + j][ntile * 16 + m] = acc[j] + bias2;
    }
    LBAR();
  };

#define KV(j) (kbuf[0][j][r][d] + kbuf[1][j][r][d])
#define COMBINE(EXPR)                                   \
  for (int e = tid; e < BR * BD; e += NTHREADS) {       \
    const int r = e >> 6, d = e & 63;                   \
    const float yv = ybuf[r][d];                        \
    atile[r][d] = (f16)(EXPR);                          \
  }                                                     \
  LBAR();

  for (int t = 0; t < TT - 1; ++t) {
    const float hstep = (ts[t + 1] - ts[t]) * 0.25f;
    for (int s = 0; s < 4; ++s) {
      feval(0);                                          // atile holds current y
      COMBINE(yv + hstep * (cA21 * KV(0)))
      feval(1);
      COMBINE(yv + hstep * (cA31 * KV(0) + cA32 * KV(1)))
      feval(2);
      COMBINE(yv + hstep * (cA41 * KV(0) + cA42 * KV(1) + cA43 * KV(2)))
      feval(3);
      COMBINE(yv + hstep * (cA51 * KV(0) + cA52 * KV(1) + cA53 * KV(2) + cA54 * KV(3)))
      feval(4);
      COMBINE(yv + hstep * (cA61 * KV(0) + cA62 * KV(1) + cA63 * KV(2) + cA64 * KV(3) + cA65 * KV(4)))
      feval(5);
      // merged y-update + stage-1 COMBINE of next substep (atile = y_new)
      for (int e = tid; e < BR * BD; e += NTHREADS) {
        const int r = e >> 6, d = e & 63;
        const float yn = ybuf[r][d] + hstep * (cB1 * KV(0) + cB2 * KV(1) + cB3 * KV(2) +
                                               cB4 * KV(3) + cB5 * KV(4) + cB6 * KV(5));
        ybuf[r][d] = yn;
        atile[r][d] = (f16)yn;
      }
      LBAR();
    }
    // save y at t+1
    for (int e = tid; e < BR * BD; e += NTHREADS) {
      const int r = e >> 6, d = e & 63;
      out[(row0 + r) * (TT * BD) + (t + 1) * BD + d] = ybuf[r][d];
    }
  }
#undef KV
#undef COMBINE
}

extern "C" void kernel_launch(void* const* d_in, const int* in_sizes, int n_in,
                              void* d_out, int out_size, void* d_ws, size_t ws_size,
                              hipStream_t stream) {
  const float* ts = (const float*)d_in[0];
  const float* y0 = (const float*)d_in[1];
  const float* W0 = (const float*)d_in[2];
  const float* b0 = (const float*)d_in[3];
  const float* W1 = (const float*)d_in[4];
  const float* b1 = (const float*)d_in[5];
  const float* W2 = (const float*)d_in[6];
  const float* b2 = (const float*)d_in[7];
  f16* wsh = (f16*)d_ws;  // needs 655360 bytes: W0h | W1h | W2h

  cvt_kernel<<<640, 512, 0, stream>>>(W0, W1, W2, wsh);
  ode_kernel<<<NBLK, NTHREADS, 0, stream>>>(ts, y0, b0, b1, b2,
                                            wsh, wsh + 32768, wsh + 294912,
                                            (float*)d_out);
}

// Round 4
// 2403.616 us; speedup vs baseline: 2.7695x; 2.7695x over previous
//
#include <hip/hip_runtime.h>
#include <stdint.h>

typedef _Float16 f16;
typedef __attribute__((ext_vector_type(8))) _Float16 f16x8;
typedef __attribute__((ext_vector_type(4))) float f32x4;

#define BD 64      // state dim D
#define HW 512     // hidden width W
#define TT 16      // time points T
#define BR 16      // batch rows per block
#define NBLK 32    // 512 / 16
#define NTHREADS 512

// lgkm-only barrier: protects LDS producer->consumer without draining vmcnt
#define LBAR() asm volatile("s_waitcnt lgkmcnt(0)\n\ts_barrier" ::: "memory")
#define WAIT_VM4() asm volatile("s_waitcnt vmcnt(4)" ::: "memory")
#define WAIT_LGKM0() asm volatile("s_waitcnt lgkmcnt(0)" ::: "memory")
#define VM_DRAIN() asm volatile("s_waitcnt vmcnt(0)" ::: "memory")

// direct L2->LDS DMA, 16B per lane, zero VGPR cost
#define GLOAD_LDS(gp, lp) __builtin_amdgcn_global_load_lds( \
    (const __attribute__((address_space(1))) void*)(gp),    \
    (__attribute__((address_space(3))) void*)(lp), 16, 0, 0)

// Tsit5 coefficients
constexpr float cA21 = 0.161f;
constexpr float cA31 = -0.008480655492356989f, cA32 = 0.335480655492357f;
constexpr float cA41 = 2.8971530571054935f, cA42 = -6.359448489975075f, cA43 = 4.3622954328695815f;
constexpr float cA51 = 5.325864828439257f, cA52 = -11.748883564062828f, cA53 = 7.4955393428898365f, cA54 = -0.09249506636175525f;
constexpr float cA61 = 5.86145544294642f, cA62 = -12.92096931784711f, cA63 = 8.159367898576159f, cA64 = -0.071584973281401f, cA65 = -0.028269050394068383f;
constexpr float cB1 = 0.09646076681806523f, cB2 = 0.01f, cB3 = 0.4798896504144996f;
constexpr float cB4 = 1.379008574103742f, cB5 = -3.290069515436081f, cB6 = 2.324710524099774f;

__device__ __forceinline__ float softplus_f(float x) {
  return fmaxf(x, 0.0f) + __logf(1.0f + __expf(-fabsf(x)));
}

// convert W0 [512,64], W1 [512,512], W2 [64,512] (row-major f32) to fp16 in ws
__global__ void cvt_kernel(const float* __restrict__ w0,
                           const float* __restrict__ w1,
                           const float* __restrict__ w2,
                           f16* __restrict__ wsh) {
  int i = blockIdx.x * 512 + threadIdx.x;
  if (i < 32768) wsh[i] = (f16)w0[i];
  else if (i < 294912) wsh[i] = (f16)w1[i - 32768];
  else if (i < 327680) wsh[i] = (f16)w2[i - 294912];
}

__global__ __launch_bounds__(NTHREADS, 2)
void ode_kernel(const float* __restrict__ ts,
                const float* __restrict__ y0,
                const float* __restrict__ b0,
                const float* __restrict__ b1,
                const float* __restrict__ b2,
                const f16* __restrict__ W0h,
                const f16* __restrict__ W1h,
                const f16* __restrict__ W2h,
                float* __restrict__ out) {
  __shared__ __align__(16) f16 h0buf[BR][HW + 8];
  __shared__ __align__(16) f16 h1buf[BR][HW + 8];
  __shared__ __align__(16) f16 atile[BR][BD + 8];
  __shared__ float kbuf[2][6][BR][BD];   // split-K halves of layer-3 output
  __shared__ float ybuf[BR][BD];
  __shared__ float hsteps[TT - 1];
  // per-wave double-buffered W1 k-tile slice: [wave][buf][64 rows x 32 f16]
  __shared__ __align__(16) f16 w1tile[8][2][2048];

  const int tid = threadIdx.x;
  const int wave = tid >> 6;
  const int lane = tid & 63;
  const int m = lane & 15;   // A-row / B-col / D-col index
  const int g = lane >> 4;   // lane group 0..3
  const int row0 = blockIdx.x * BR;
  const int cbase = wave * 64;   // layer1/2 output-column base for this wave
  const int ntile = wave & 3;    // layer3 output col tile
  const int kh = wave >> 2;      // layer3 K half
  const int pp = g ^ ((m >> 1) & 3);   // read-side XOR swizzle chunk

  // ---- W1 stage source pointers (pre-swizzled global addresses, m173 pattern) ----
  const int lr = lane >> 2;                                  // row within 16-row group
  const int swz = ((lane & 3) ^ ((lane >> 3) & 3)) * 8;      // swizzled col chunk
  const f16* w1src[4];
#pragma unroll
  for (int i = 0; i < 4; ++i)
    w1src[i] = W1h + (size_t)(cbase + i * 16 + lr) * HW + swz;

  // ---- loop-invariant weights/biases in registers (W0, W2 only: 64 VGPR) ----
  f16x8 w0r[2][4];
#pragma unroll
  for (int kt = 0; kt < 2; ++kt)
#pragma unroll
    for (int nt = 0; nt < 4; ++nt)
      w0r[kt][nt] = *(const f16x8*)&W0h[(cbase + nt * 16 + m) * BD + kt * 32 + g * 8];
  f16x8 w2r[8];
#pragma unroll
  for (int kt = 0; kt < 8; ++kt)
    w2r[kt] = *(const f16x8*)&W2h[(ntile * 16 + m) * HW + kh * 256 + kt * 32 + g * 8];
  float bias0[4], bias1[4];
#pragma unroll
  for (int nt = 0; nt < 4; ++nt) {
    bias0[nt] = b0[cbase + nt * 16 + m];
    bias1[nt] = b1[cbase + nt * 16 + m];
  }
  const float bias2 = (kh == 0) ? b2[ntile * 16 + m] : 0.0f;

  // ---- init: y0 -> LDS, t=0 output, hsteps table (keeps ts off vmcnt later) ----
  for (int e = tid; e < BR * BD; e += NTHREADS) {
    const int r = e >> 6, d = e & 63;
    const float v = y0[(row0 + r) * BD + d];
    ybuf[r][d] = v;
    atile[r][d] = (f16)v;
    out[(row0 + r) * (TT * BD) + d] = v;
  }
  if (tid < TT - 1) hsteps[tid] = (ts[tid + 1] - ts[tid]) * 0.25f;

  // prologue: stage W1 tiles 0,1 (8 loads in flight)
#pragma unroll
  for (int i = 0; i < 4; ++i) GLOAD_LDS(w1src[i], &w1tile[wave][0][i * 512]);
#pragma unroll
  for (int i = 0; i < 4; ++i) GLOAD_LDS(w1src[i] + 32, &w1tile[wave][1][i * 512]);
  LBAR();

  // f(atile) -> kbuf[*][kidx]
  auto feval = [&](int kidx) {
    // ---- layer 1: h0 = softplus(atile @ W0^T + b0); B in registers
    {
      f32x4 acc[4] = {{0.f,0.f,0.f,0.f},{0.f,0.f,0.f,0.f},{0.f,0.f,0.f,0.f},{0.f,0.f,0.f,0.f}};
#pragma unroll
      for (int kt = 0; kt < 2; ++kt) {
        const f16x8 a = *(const f16x8*)&atile[m][kt * 32 + g * 8];
#pragma unroll
        for (int nt = 0; nt < 4; ++nt)
          acc[nt] = __builtin_amdgcn_mfma_f32_16x16x32_f16(a, w0r[kt][nt], acc[nt], 0, 0, 0);
      }
#pragma unroll
      for (int nt = 0; nt < 4; ++nt) {
        const int n = cbase + nt * 16 + m;
#pragma unroll
        for (int j = 0; j < 4; ++j)
          h0buf[g * 4 + j][n] = (f16)softplus_f(acc[nt][j] + bias0[nt]);
      }
    }
    LBAR();
    // ---- layer 2: h1 = softplus(h0 @ W1^T + b1)
    // per-wave LDS double-buffer, counted vmcnt(4), no barriers (self-produced slice)
    {
      f32x4 acc[4] = {{0.f,0.f,0.f,0.f},{0.f,0.f,0.f,0.f},{0.f,0.f,0.f,0.f},{0.f,0.f,0.f,0.f}};
#pragma unroll
      for (int kt = 0; kt < 16; ++kt) {
        WAIT_VM4();                       // tile kt resident; kt+1 still in flight
        const f16x8 a = *(const f16x8*)&h0buf[m][kt * 32 + g * 8];
        f16x8 bfr[4];
#pragma unroll
        for (int nt = 0; nt < 4; ++nt)
          bfr[nt] = *(const f16x8*)&w1tile[wave][kt & 1][(nt * 16 + m) * 32 + pp * 8];
        WAIT_LGKM0();                     // reads retired -> safe to overwrite buffer
        {
          const int ktn = (kt < 14) ? kt + 2 : kt - 14;  // 14,15 stage next feval's 0,1
#pragma unroll
          for (int i = 0; i < 4; ++i)
            GLOAD_LDS(w1src[i] + ktn * 32, &w1tile[wave][kt & 1][i * 512]);
        }
#pragma unroll
        for (int nt = 0; nt < 4; ++nt)
          acc[nt] = __builtin_amdgcn_mfma_f32_16x16x32_f16(a, bfr[nt], acc[nt], 0, 0, 0);
      }
#pragma unroll
      for (int nt = 0; nt < 4; ++nt) {
        const int n = cbase + nt * 16 + m;
#pragma unroll
        for (int j = 0; j < 4; ++j)
          h1buf[g * 4 + j][n] = (f16)softplus_f(acc[nt][j] + bias1[nt]);
      }
    }
    LBAR();
    // ---- layer 3: k = h1 @ W2^T + b2; split-K across wave halves, B in registers
    {
      f32x4 acc = {0.f, 0.f, 0.f, 0.f};
#pragma unroll
      for (int kt = 0; kt < 8; ++kt) {
        const f16x8 a = *(const f16x8*)&h1buf[m][kh * 256 + kt * 32 + g * 8];
        acc = __builtin_amdgcn_mfma_f32_16x16x32_f16(a, w2r[kt], acc, 0, 0, 0);
      }
#pragma unroll
      for (int j = 0; j < 4; ++j)
        kbuf[kh][kidx][g * 4 + j][ntile * 16 + m] = acc[j] + bias2;
    }
    LBAR();
  };

#define KV(j) (kbuf[0][j][r][d] + kbuf[1][j][r][d])
#define COMBINE(EXPR)                                   \
  for (int e = tid; e < BR * BD; e += NTHREADS) {       \
    const int r = e >> 6, d = e & 63;                   \
    const float yv = ybuf[r][d];                        \
    atile[r][d] = (f16)(EXPR);                          \
  }                                                     \
  LBAR();

  for (int t = 0; t < TT - 1; ++t) {
    const float hstep = hsteps[t];
    for (int s = 0; s < 4; ++s) {
      feval(0);                                          // atile holds current y
      COMBINE(yv + hstep * (cA21 * KV(0)))
      feval(1);
      COMBINE(yv + hstep * (cA31 * KV(0) + cA32 * KV(1)))
      feval(2);
      COMBINE(yv + hstep * (cA41 * KV(0) + cA42 * KV(1) + cA43 * KV(2)))
      feval(3);
      COMBINE(yv + hstep * (cA51 * KV(0) + cA52 * KV(1) + cA53 * KV(2) + cA54 * KV(3)))
      feval(4);
      COMBINE(yv + hstep * (cA61 * KV(0) + cA62 * KV(1) + cA63 * KV(2) + cA64 * KV(3) + cA65 * KV(4)))
      feval(5);
      // merged y-update + stage-1 COMBINE of next substep
      for (int e = tid; e < BR * BD; e += NTHREADS) {
        const int r = e >> 6, d = e & 63;
        const float yn = ybuf[r][d] + hstep * (cB1 * KV(0) + cB2 * KV(1) + cB3 * KV(2) +
                                               cB4 * KV(3) + cB5 * KV(4) + cB6 * KV(5));
        ybuf[r][d] = yn;
        atile[r][d] = (f16)yn;
      }
      LBAR();
    }
    // save y at t+1, then drain stores so they don't pollute counted vmcnt
    for (int e = tid; e < BR * BD; e += NTHREADS) {
      const int r = e >> 6, d = e & 63;
      out[(row0 + r) * (TT * BD) + (t + 1) * BD + d] = ybuf[r][d];
    }
    VM_DRAIN();
  }
#undef KV
#undef COMBINE
}

extern "C" void kernel_launch(void* const* d_in, const int* in_sizes, int n_in,
                              void* d_out, int out_size, void* d_ws, size_t ws_size,
                              hipStream_t stream) {
  const float* ts = (const float*)d_in[0];
  const float* y0 = (const float*)d_in[1];
  const float* W0 = (const float*)d_in[2];
  const float* b0 = (const float*)d_in[3];
  const float* W1 = (const float*)d_in[4];
  const float* b1 = (const float*)d_in[5];
  const float* W2 = (const float*)d_in[6];
  const float* b2 = (const float*)d_in[7];
  f16* wsh = (f16*)d_ws;  // 655360 bytes: W0h | W1h | W2h

  cvt_kernel<<<640, 512, 0, stream>>>(W0, W1, W2, wsh);
  ode_kernel<<<NBLK, NTHREADS, 0, stream>>>(ts, y0, b0, b1, b2,
                                            wsh, wsh + 32768, wsh + 294912,
                                            (float*)d_out);
}

// Round 5
// 1635.920 us; speedup vs baseline: 4.0691x; 1.4693x over previous
//
#include <hip/hip_runtime.h>
#include <stdint.h>

typedef _Float16 f16;
typedef __attribute__((ext_vector_type(8))) _Float16 f16x8;
typedef __attribute__((ext_vector_type(4))) float f32x4;

#define BD 64      // state dim D
#define HW 512     // hidden width W
#define TT 16      // time points T
#define BR 16      // batch rows per group
#define NTHREADS 512
#define NGRP 32    // batch groups (512/16)
#define NCU 4      // CUs per group (W1 split 4 ways -> 128 KB LDS-resident each)

// lgkm-only barrier: LDS producer->consumer, no vmcnt drain
#define LBAR() asm volatile("s_waitcnt lgkmcnt(0)\n\ts_barrier" ::: "memory")
#define VM_DRAIN() asm volatile("s_waitcnt vmcnt(0)" ::: "memory")

// Tsit5 coefficients
constexpr float cA21 = 0.161f;
constexpr float cA31 = -0.008480655492356989f, cA32 = 0.335480655492357f;
constexpr float cA41 = 2.8971530571054935f, cA42 = -6.359448489975075f, cA43 = 4.3622954328695815f;
constexpr float cA51 = 5.325864828439257f, cA52 = -11.748883564062828f, cA53 = 7.4955393428898365f, cA54 = -0.09249506636175525f;
constexpr float cA61 = 5.86145544294642f, cA62 = -12.92096931784711f, cA63 = 8.159367898576159f, cA64 = -0.071584973281401f, cA65 = -0.028269050394068383f;
constexpr float cB1 = 0.09646076681806523f, cB2 = 0.01f, cB3 = 0.4798896504144996f;
constexpr float cB4 = 1.379008574103742f, cB5 = -3.290069515436081f, cB6 = 2.324710524099774f;

__device__ __forceinline__ float softplus_f(float x) {
  return fmaxf(x, 0.0f) + __logf(1.0f + __expf(-fabsf(x)));
}

// convert W0 [512,64], W1 [512,512], W2 [64,512] (row-major f32) to fp16 in ws
__global__ void cvt_kernel(const float* __restrict__ w0,
                           const float* __restrict__ w1,
                           const float* __restrict__ w2,
                           f16* __restrict__ wsh) {
  int i = blockIdx.x * 512 + threadIdx.x;
  if (i < 32768) wsh[i] = (f16)w0[i];
  else if (i < 294912) wsh[i] = (f16)w1[i - 32768];
  else if (i < 327680) wsh[i] = (f16)w2[i - 294912];
}

__global__ __launch_bounds__(NTHREADS)
void ode_kernel(const float* __restrict__ ts,
                const float* __restrict__ y0,
                const float* __restrict__ b0,
                const float* __restrict__ b1,
                const float* __restrict__ b2,
                const f16* __restrict__ W0h,
                const f16* __restrict__ W1h,
                const f16* __restrict__ W2h,
                float* __restrict__ out,
                float* __restrict__ partials,
                unsigned* __restrict__ flags) {
  // resident swizzled W1 slice: 128 rows x 512 cols fp16 = 131072 B
  __shared__ __align__(16) f16 w1s[128 * HW];
  __shared__ __align__(16) f16 h0buf[BR][HW + 8];
  __shared__ __align__(16) f16 h1buf[BR][128 + 8];
  __shared__ __align__(16) f16 atile[BR][BD + 8];
  __shared__ float hsteps[TT - 1];

  const int tid  = threadIdx.x;
  const int wave = tid >> 6;
  const int lane = tid & 63;
  const int m = lane & 15;   // MFMA col index
  const int g = lane >> 4;   // lane group 0..3
  const int b = blockIdx.x;
  const int grp = b & 31;    // batch group; members {grp, grp+32, +64, +96} share an XCD
  const int cuj = b >> 5;    // which quarter of W1/h1/K this CU owns
  const int row0 = grp * BR;
  const int cbase = wave * 64;  // layer-1 output-col base (full 512 across 8 waves)
  const int ntile = wave & 3;   // layer-3 output col tile (waves 4-7 duplicate)

  // per-thread output element ownership: elems (r0,d) and (r0+8,d)
  const int r0 = tid >> 6, d = tid & 63;

  // ---- loop-invariant registers ----
  f16x8 w0r[2][4];
#pragma unroll
  for (int kt = 0; kt < 2; ++kt)
#pragma unroll
    for (int nt = 0; nt < 4; ++nt)
      w0r[kt][nt] = *(const f16x8*)&W0h[(cbase + nt * 16 + m) * BD + kt * 32 + g * 8];
  f16x8 w2r[4];  // W2 K-slice [cuj*128, +128) for out tile ntile
#pragma unroll
  for (int kt = 0; kt < 4; ++kt)
    w2r[kt] = *(const f16x8*)&W2h[(ntile * 16 + m) * HW + cuj * 128 + kt * 32 + g * 8];
  float bias0[4];
#pragma unroll
  for (int nt = 0; nt < 4; ++nt) bias0[nt] = b0[cbase + nt * 16 + m];
  const float bias1 = b1[cuj * 128 + wave * 16 + m];
  const float b2d = b2[d];

  // ---- y state in registers ----
  float yreg0 = y0[(row0 + r0) * BD + d];
  float yreg1 = y0[(row0 + r0 + 8) * BD + d];
  atile[r0][d] = (f16)yreg0;
  atile[r0 + 8][d] = (f16)yreg1;
  if (cuj == 0) {
    out[(row0 + r0) * (TT * BD) + d] = yreg0;
    out[(row0 + r0 + 8) * (TT * BD) + d] = yreg1;
  }
  if (tid < TT - 1) hsteps[tid] = (ts[tid + 1] - ts[tid]) * 0.25f;

  // ---- stage resident W1 slice into LDS, XOR-swizzled: byte ^= (row&7)<<4 ----
  for (int idx = tid; idx < 128 * 64; idx += NTHREADS) {
    const int row = idx >> 6, ch = idx & 63;           // ch = 16B chunk (8 f16)
    const f16x8 v = *(const f16x8*)&W1h[(size_t)(cuj * 128 + row) * HW + ch * 8];
    *(f16x8*)((char*)w1s + row * 1024 + ((ch * 16) ^ ((row & 7) << 4))) = v;
  }
  LBAR();

  const int brow = wave * 16 + m;            // this lane's W1-slice row (local)
  const char* const w1base = (const char*)w1s + brow * 1024;
  const int rsw = (brow & 7) << 4;           // read-side swizzle

  float k1a, k1b, k2a, k2b, k3a, k3b, k4a, k4b, k5a, k5b, k6a, k6b;
  int fstep = 0;
  unsigned* const flagp = &flags[grp * 32];

// one MLP eval of f(atile); distributes k into (KA,KB) registers on every CU
#define FEVAL(ST, KA, KB)                                                        \
  do {                                                                           \
    /* layer 1: full h0 (replicated), W0 in regs */                              \
    {                                                                            \
      f32x4 acc[4] = {{0,0,0,0},{0,0,0,0},{0,0,0,0},{0,0,0,0}};                  \
      _Pragma("unroll")                                                          \
      for (int kt = 0; kt < 2; ++kt) {                                           \
        const f16x8 a = *(const f16x8*)&atile[m][kt * 32 + g * 8];               \
        _Pragma("unroll")                                                        \
        for (int nt = 0; nt < 4; ++nt)                                           \
          acc[nt] = __builtin_amdgcn_mfma_f32_16x16x32_f16(a, w0r[kt][nt], acc[nt], 0, 0, 0); \
      }                                                                          \
      _Pragma("unroll")                                                          \
      for (int nt = 0; nt < 4; ++nt) {                                           \
        const int n = cbase + nt * 16 + m;                                       \
        _Pragma("unroll")                                                        \
        for (int j = 0; j < 4; ++j)                                              \
          h0buf[g * 4 + j][n] = (f16)softplus_f(acc[nt][j] + bias0[nt]);         \
      }                                                                          \
    }                                                                            \
    LBAR();                                                                      \
    /* layer 2: 16 local h1 cols per wave, W1 from resident swizzled LDS */      \
    {                                                                            \
      f32x4 acc1 = {0, 0, 0, 0};                                                 \
      _Pragma("unroll")                                                          \
      for (int kt = 0; kt < 16; ++kt) {                                          \
        const f16x8 a = *(const f16x8*)&h0buf[m][kt * 32 + g * 8];               \
        const f16x8 bb = *(const f16x8*)(w1base + ((kt * 64 + g * 16) ^ rsw));   \
        acc1 = __builtin_amdgcn_mfma_f32_16x16x32_f16(a, bb, acc1, 0, 0, 0);     \
      }                                                                          \
      _Pragma("unroll")                                                          \
      for (int j = 0; j < 4; ++j)                                                \
        h1buf[g * 4 + j][wave * 16 + m] = (f16)softplus_f(acc1[j] + bias1);      \
    }                                                                            \
    LBAR();                                                                      \
    /* layer 3: split-K partial (local K=128), exchange via agent-scope ws */    \
    {                                                                            \
      f32x4 acc3 = {0, 0, 0, 0};                                                 \
      _Pragma("unroll")                                                          \
      for (int kt = 0; kt < 4; ++kt) {                                           \
        const f16x8 a = *(const f16x8*)&h1buf[m][kt * 32 + g * 8];               \
        acc3 = __builtin_amdgcn_mfma_f32_16x16x32_f16(a, w2r[kt], acc3, 0, 0, 0);\
      }                                                                          \
      float* const pb = partials + ((size_t)(grp * 6 + (ST)) * 4 + cuj) * 1024;  \
      if (wave < 4) {                                                            \
        _Pragma("unroll")                                                        \
        for (int j = 0; j < 4; ++j)                                              \
          __hip_atomic_store(&pb[(g * 4 + j) * 64 + ntile * 16 + m], acc3[j],    \
                             __ATOMIC_RELAXED, __HIP_MEMORY_SCOPE_AGENT);        \
      }                                                                          \
      VM_DRAIN();                                                                \
      __syncthreads();                                                           \
      if (tid == 0) {                                                            \
        __hip_atomic_fetch_add(flagp, 1u, __ATOMIC_RELEASE, __HIP_MEMORY_SCOPE_AGENT); \
        const unsigned tgt = 4u * (unsigned)fstep;                               \
        while (__hip_atomic_load(flagp, __ATOMIC_ACQUIRE, __HIP_MEMORY_SCOPE_AGENT) < tgt) \
          __builtin_amdgcn_s_sleep(1);                                           \
      }                                                                          \
      __syncthreads();                                                           \
      float s0 = 0.f, s1 = 0.f;                                                  \
      const float* const q = partials + (size_t)(grp * 6 + (ST)) * 4 * 1024;     \
      _Pragma("unroll")                                                          \
      for (int c = 0; c < 4; ++c) {                                              \
        s0 += __hip_atomic_load(q + c * 1024 + tid, __ATOMIC_RELAXED, __HIP_MEMORY_SCOPE_AGENT); \
        s1 += __hip_atomic_load(q + c * 1024 + tid + 512, __ATOMIC_RELAXED, __HIP_MEMORY_SCOPE_AGENT); \
      }                                                                          \
      KA = s0 + b2d;                                                             \
      KB = s1 + b2d;                                                             \
    }                                                                            \
  } while (0)

#define PUT_ATILE(E0, E1) \
  atile[r0][d] = (f16)(E0); atile[r0 + 8][d] = (f16)(E1); LBAR();

  for (int t = 0; t < TT - 1; ++t) {
    const float h = hsteps[t];
    for (int s = 0; s < 4; ++s) {
      ++fstep; FEVAL(0, k1a, k1b);
      PUT_ATILE(yreg0 + h * (cA21 * k1a), yreg1 + h * (cA21 * k1b))
      ++fstep; FEVAL(1, k2a, k2b);
      PUT_ATILE(yreg0 + h * (cA31 * k1a + cA32 * k2a),
                yreg1 + h * (cA31 * k1b + cA32 * k2b))
      ++fstep; FEVAL(2, k3a, k3b);
      PUT_ATILE(yreg0 + h * (cA41 * k1a + cA42 * k2a + cA43 * k3a),
                yreg1 + h * (cA41 * k1b + cA42 * k2b + cA43 * k3b))
      ++fstep; FEVAL(3, k4a, k4b);
      PUT_ATILE(yreg0 + h * (cA51 * k1a + cA52 * k2a + cA53 * k3a + cA54 * k4a),
                yreg1 + h * (cA51 * k1b + cA52 * k2b + cA53 * k3b + cA54 * k4b))
      ++fstep; FEVAL(4, k5a, k5b);
      PUT_ATILE(yreg0 + h * (cA61 * k1a + cA62 * k2a + cA63 * k3a + cA64 * k4a + cA65 * k5a),
                yreg1 + h * (cA61 * k1b + cA62 * k2b + cA63 * k3b + cA64 * k4b + cA65 * k5b))
      ++fstep; FEVAL(5, k6a, k6b);
      yreg0 += h * (cB1 * k1a + cB2 * k2a + cB3 * k3a + cB4 * k4a + cB5 * k5a + cB6 * k6a);
      yreg1 += h * (cB1 * k1b + cB2 * k2b + cB3 * k3b + cB4 * k4b + cB5 * k5b + cB6 * k6b);
      PUT_ATILE(yreg0, yreg1)
    }
    if (cuj == 0) {
      out[(row0 + r0) * (TT * BD) + (t + 1) * BD + d] = yreg0;
      out[(row0 + r0 + 8) * (TT * BD) + (t + 1) * BD + d] = yreg1;
    }
  }
#undef FEVAL
#undef PUT_ATILE
}

extern "C" void kernel_launch(void* const* d_in, const int* in_sizes, int n_in,
                              void* d_out, int out_size, void* d_ws, size_t ws_size,
                              hipStream_t stream) {
  const float* ts = (const float*)d_in[0];
  const float* y0 = (const float*)d_in[1];
  const float* W0 = (const float*)d_in[2];
  const float* b0 = (const float*)d_in[3];
  const float* W1 = (const float*)d_in[4];
  const float* b1 = (const float*)d_in[5];
  const float* W2 = (const float*)d_in[6];
  const float* b2 = (const float*)d_in[7];
  // ws layout: [0,640K) fp16 weights | [640K,644K) flags | [648K, 648K+3M) k-partials
  f16* wsh = (f16*)d_ws;
  unsigned* flags = (unsigned*)((char*)d_ws + 655360);
  float* partials = (float*)((char*)d_ws + 663552);  // needs ws_size >= ~3.9 MB

  cvt_kernel<<<640, 512, 0, stream>>>(W0, W1, W2, wsh);
  hipMemsetAsync(flags, 0, 4096, stream);
  ode_kernel<<<NGRP * NCU, NTHREADS, 0, stream>>>(ts, y0, b0, b1, b2,
                                                  wsh, wsh + 32768, wsh + 294912,
                                                  (float*)d_out, partials, flags);
}